// Round 1
// baseline (580.001 us; speedup 1.0000x reference)
//
#include <hip/hip_runtime.h>
#include <math.h>

#define BB   64
#define FF   1024
#define HIDD 2048
#define NHH  4
#define KSS  4
#define HDD  512
#define EPSV 1e-6f
#define INV_SQRT_HD 0.04419417382415922f  // 1/sqrt(512)

// ---------------- K1: up GEMM split-K: part[kc][b][c] ----------------
// grid (16 coltiles, 4 btiles, 4 kchunks) = 256 blocks, block 256.
// float4 A-reads: 1 ds_read_b128 per 4 FMAs (was 1 ds_read_b32 per FMA).
__global__ __launch_bounds__(256) void k_up_part(const float* __restrict__ A,
                                                 const float* __restrict__ W,
                                                 float* __restrict__ part) {
    const int tid = threadIdx.x;
    const int c  = blockIdx.x * 256 + tid;
    const int b0 = blockIdx.y * 16;
    const int k0 = blockIdx.z * 256;
    __shared__ float As[16 * 256];
#pragma unroll
    for (int j = 0; j < 16; ++j)
        As[j * 256 + tid] = A[(size_t)(b0 + j) * FF + k0 + tid];
    __syncthreads();
    float acc[16];
#pragma unroll
    for (int i = 0; i < 16; ++i) acc[i] = 0.f;
    const float* __restrict__ wp = W + (size_t)k0 * (2 * HIDD) + c;
#pragma unroll 2
    for (int f4 = 0; f4 < 64; ++f4) {
        const float w0 = wp[(size_t)(4*f4 + 0) * (2 * HIDD)];
        const float w1 = wp[(size_t)(4*f4 + 1) * (2 * HIDD)];
        const float w2 = wp[(size_t)(4*f4 + 2) * (2 * HIDD)];
        const float w3 = wp[(size_t)(4*f4 + 3) * (2 * HIDD)];
#pragma unroll
        for (int i = 0; i < 16; ++i) {
            const float4 a = *(const float4*)(As + i * 256 + f4 * 4);
            acc[i] += a.x * w0 + a.y * w1 + a.z * w2 + a.w * w3;
        }
    }
    float* __restrict__ pp = part + ((size_t)blockIdx.z * BB + b0) * (2 * HIDD) + c;
#pragma unroll
    for (int i = 0; i < 16; ++i) pp[(size_t)i * (2 * HIDD)] = acc[i];
}

// ---------------- K2: fused up-reduce + conv + silu + qkv + gates + n/den ----------------
// grid 64 (one block per b), block 512. Thread n owns hid elements h0=n*4 .. h0+3.
__global__ __launch_bounds__(512) void k_mid(
    const float* __restrict__ part_up, const float* __restrict__ conv_state,
    const float* __restrict__ conv_w, const float* __restrict__ conv_b,
    const float* __restrict__ Wq, const float* __restrict__ Wk, const float* __restrict__ Wv,
    const float* __restrict__ Wi, const float* __restrict__ bi,
    const float* __restrict__ Wf, const float* __restrict__ bf,
    const float* __restrict__ mstate_in, const float* __restrict__ nstate_in,
    const float* __restrict__ skip,
    float* __restrict__ out_cs, float* __restrict__ out_m, float* __restrict__ out_n,
    float* __restrict__ sact, float* __restrict__ zsil,
    float* __restrict__ qb, float* __restrict__ kb, float* __restrict__ vb,
    float* __restrict__ scal) {
    const int b  = blockIdx.x;
    const int n  = threadIdx.x;
    const int h0 = n * 4;

    // ---- inline split-K reduce of x-half ----
    float4 x4 = *(const float4*)(part_up + (size_t)b * (2 * HIDD) + h0);
#pragma unroll
    for (int kc = 1; kc < 4; ++kc) {
        const float4 p = *(const float4*)(part_up + ((size_t)kc * BB + b) * (2 * HIDD) + h0);
        x4.x += p.x; x4.y += p.y; x4.z += p.z; x4.w += p.w;
    }
    // ---- inline split-K reduce of z-half + silu(z) ----
    float4 z4 = *(const float4*)(part_up + (size_t)b * (2 * HIDD) + HIDD + h0);
#pragma unroll
    for (int kc = 1; kc < 4; ++kc) {
        const float4 p = *(const float4*)(part_up + ((size_t)kc * BB + b) * (2 * HIDD) + HIDD + h0);
        z4.x += p.x; z4.y += p.y; z4.z += p.z; z4.w += p.w;
    }
    float4 zs;
    zs.x = z4.x / (1.f + expf(-z4.x));
    zs.y = z4.y / (1.f + expf(-z4.y));
    zs.z = z4.z / (1.f + expf(-z4.z));
    zs.w = z4.w / (1.f + expf(-z4.w));
    *(float4*)(zsil + (size_t)b * HIDD + h0) = zs;

    // ---- conv state shift + conv + silu ----
    const float4 cs1 = *(const float4*)(conv_state + (size_t)b * KSS * HIDD + 1 * HIDD + h0);
    const float4 cs2 = *(const float4*)(conv_state + (size_t)b * KSS * HIDD + 2 * HIDD + h0);
    const float4 cs3 = *(const float4*)(conv_state + (size_t)b * KSS * HIDD + 3 * HIDD + h0);
    *(float4*)(out_cs + (size_t)b * KSS * HIDD + 0 * HIDD + h0) = cs1;
    *(float4*)(out_cs + (size_t)b * KSS * HIDD + 1 * HIDD + h0) = cs2;
    *(float4*)(out_cs + (size_t)b * KSS * HIDD + 2 * HIDD + h0) = cs3;
    *(float4*)(out_cs + (size_t)b * KSS * HIDD + 3 * HIDD + h0) = x4;
    const float4 cw0 = *(const float4*)(conv_w + 0 * HIDD + h0);
    const float4 cw1 = *(const float4*)(conv_w + 1 * HIDD + h0);
    const float4 cw2 = *(const float4*)(conv_w + 2 * HIDD + h0);
    const float4 cw3 = *(const float4*)(conv_w + 3 * HIDD + h0);
    const float4 cb  = *(const float4*)(conv_b + h0);
    float4 cx;
    cx.x = cs1.x*cw0.x + cs2.x*cw1.x + cs3.x*cw2.x + x4.x*cw3.x + cb.x;
    cx.y = cs1.y*cw0.y + cs2.y*cw1.y + cs3.y*cw2.y + x4.y*cw3.y + cb.y;
    cx.z = cs1.z*cw0.z + cs2.z*cw1.z + cs3.z*cw2.z + x4.z*cw3.z + cb.z;
    cx.w = cs1.w*cw0.w + cs2.w*cw1.w + cs3.w*cw2.w + x4.w*cw3.w + cb.w;
    float4 a4;
    a4.x = cx.x / (1.f + expf(-cx.x));
    a4.y = cx.y / (1.f + expf(-cx.y));
    a4.z = cx.z / (1.f + expf(-cx.z));
    a4.w = cx.w / (1.f + expf(-cx.w));
    const float4 sk = *(const float4*)(skip + h0);
    float4 sa;
    sa.x = sk.x * a4.x; sa.y = sk.y * a4.y; sa.z = sk.z * a4.z; sa.w = sk.w * a4.w;
    *(float4*)(sact + (size_t)b * HIDD + h0) = sa;

    // ---- blockdiag q/k/v ----
    const float4 q0 = *(const float4*)(Wq + (size_t)n * 16 + 0);
    const float4 q1 = *(const float4*)(Wq + (size_t)n * 16 + 4);
    const float4 q2 = *(const float4*)(Wq + (size_t)n * 16 + 8);
    const float4 q3 = *(const float4*)(Wq + (size_t)n * 16 + 12);
    float4 qv4;
    qv4.x = a4.x*q0.x + a4.y*q1.x + a4.z*q2.x + a4.w*q3.x;
    qv4.y = a4.x*q0.y + a4.y*q1.y + a4.z*q2.y + a4.w*q3.y;
    qv4.z = a4.x*q0.z + a4.y*q1.z + a4.z*q2.z + a4.w*q3.z;
    qv4.w = a4.x*q0.w + a4.y*q1.w + a4.z*q2.w + a4.w*q3.w;
    *(float4*)(qb + (size_t)b * HIDD + h0) = qv4;
    const float4 k0v = *(const float4*)(Wk + (size_t)n * 16 + 0);
    const float4 k1v = *(const float4*)(Wk + (size_t)n * 16 + 4);
    const float4 k2v = *(const float4*)(Wk + (size_t)n * 16 + 8);
    const float4 k3v = *(const float4*)(Wk + (size_t)n * 16 + 12);
    float4 kv4;
    kv4.x = a4.x*k0v.x + a4.y*k1v.x + a4.z*k2v.x + a4.w*k3v.x;
    kv4.y = a4.x*k0v.y + a4.y*k1v.y + a4.z*k2v.y + a4.w*k3v.y;
    kv4.z = a4.x*k0v.z + a4.y*k1v.z + a4.z*k2v.z + a4.w*k3v.z;
    kv4.w = a4.x*k0v.w + a4.y*k1v.w + a4.z*k2v.w + a4.w*k3v.w;
    *(float4*)(kb + (size_t)b * HIDD + h0) = kv4;
    const float4 v0 = *(const float4*)(Wv + (size_t)n * 16 + 0);
    const float4 v1 = *(const float4*)(Wv + (size_t)n * 16 + 4);
    const float4 v2 = *(const float4*)(Wv + (size_t)n * 16 + 8);
    const float4 v3 = *(const float4*)(Wv + (size_t)n * 16 + 12);
    float4 vv4;
    vv4.x = x4.x*v0.x + x4.y*v1.x + x4.z*v2.x + x4.w*v3.x;
    vv4.y = x4.x*v0.y + x4.y*v1.y + x4.z*v2.y + x4.w*v3.y;
    vv4.z = x4.x*v0.z + x4.y*v1.z + x4.z*v2.z + x4.w*v3.z;
    vv4.w = x4.x*v0.w + x4.y*v1.w + x4.z*v2.w + x4.w*v3.w;
    *(float4*)(vb + (size_t)b * HIDD + h0) = vv4;

    // ---- gate reductions i/f for 4 heads (wave-shuffle, float4 Wi/Wf rows) ----
    float si0 = 0.f, si1 = 0.f, si2 = 0.f, si3 = 0.f;
    float sf0 = 0.f, sf1 = 0.f, sf2 = 0.f, sf3 = 0.f;
#define GATE_R(comp, r) { \
    const float qr = qv4.comp, kr = kv4.comp, vr = vv4.comp; \
    const float4 wq_ = *(const float4*)(Wi + (size_t)(h0 + (r)) * NHH); \
    const float4 wk_ = *(const float4*)(Wi + (size_t)(HIDD + h0 + (r)) * NHH); \
    const float4 wv_ = *(const float4*)(Wi + (size_t)(2*HIDD + h0 + (r)) * NHH); \
    si0 += qr*wq_.x + kr*wk_.x + vr*wv_.x; \
    si1 += qr*wq_.y + kr*wk_.y + vr*wv_.y; \
    si2 += qr*wq_.z + kr*wk_.z + vr*wv_.z; \
    si3 += qr*wq_.w + kr*wk_.w + vr*wv_.w; \
    const float4 fq_ = *(const float4*)(Wf + (size_t)(h0 + (r)) * NHH); \
    const float4 fk_ = *(const float4*)(Wf + (size_t)(HIDD + h0 + (r)) * NHH); \
    const float4 fv_ = *(const float4*)(Wf + (size_t)(2*HIDD + h0 + (r)) * NHH); \
    sf0 += qr*fq_.x + kr*fk_.x + vr*fv_.x; \
    sf1 += qr*fq_.y + kr*fk_.y + vr*fv_.y; \
    sf2 += qr*fq_.z + kr*fk_.z + vr*fv_.z; \
    sf3 += qr*fq_.w + kr*fk_.w + vr*fv_.w; \
}
    GATE_R(x, 0) GATE_R(y, 1) GATE_R(z, 2) GATE_R(w, 3)
#undef GATE_R
#pragma unroll
    for (int off = 32; off > 0; off >>= 1) {
        si0 += __shfl_down(si0, off); si1 += __shfl_down(si1, off);
        si2 += __shfl_down(si2, off); si3 += __shfl_down(si3, off);
        sf0 += __shfl_down(sf0, off); sf1 += __shfl_down(sf1, off);
        sf2 += __shfl_down(sf2, off); sf3 += __shfl_down(sf3, off);
    }
    const int lane = n & 63, wv = n >> 6;
    __shared__ float Ls[8][8];
    if (lane == 0) {
        Ls[wv][0] = si0; Ls[wv][1] = si1; Ls[wv][2] = si2; Ls[wv][3] = si3;
        Ls[wv][4] = sf0; Ls[wv][5] = sf1; Ls[wv][6] = sf2; Ls[wv][7] = sf3;
    }
    __syncthreads();
    __shared__ float bcst[4][3];  // f_p, ik, exp(-m_new) per head
    if (n < 4) {
        float it = bi[n], ft = bf[n];
#pragma unroll
        for (int w = 0; w < 8; ++w) { it += Ls[w][n]; ft += Ls[w][4 + n]; }
        const float log_f = fminf(ft, 0.f) - log1pf(expf(-fabsf(ft)));
        const float m_old = mstate_in[b * NHH + n];
        const float m_new = fmaxf(log_f + m_old, it);
        out_m[b * NHH + n] = m_new;
        const float f_p = expf(log_f + m_old - m_new);
        const float ikv = expf(it - m_new) * INV_SQRT_HD;
        bcst[n][0] = f_p; bcst[n][1] = ikv; bcst[n][2] = expf(-m_new);
        float* sc = scal + (size_t)(b * NHH + n) * 4;
        sc[0] = f_p; sc[1] = ikv;
    }
    __syncthreads();

    // ---- n_new + den ----
    const int h  = n >> 7;
    const int bh = b * NHH + h;
    const float f_p = bcst[h][0], ikv = bcst[h][1];
    const int d0 = (n & 127) * 4;
    const float4 nin = *(const float4*)(nstate_in + (size_t)bh * HDD + d0);
    float4 nn;
    nn.x = f_p * nin.x + ikv * kv4.x;
    nn.y = f_p * nin.y + ikv * kv4.y;
    nn.z = f_p * nin.z + ikv * kv4.z;
    nn.w = f_p * nin.w + ikv * kv4.w;
    *(float4*)(out_n + (size_t)bh * HDD + d0) = nn;
    float qn = qv4.x * nn.x + qv4.y * nn.y + qv4.z * nn.z + qv4.w * nn.w;
#pragma unroll
    for (int off = 32; off > 0; off >>= 1) qn += __shfl_down(qn, off);
    __shared__ float qnl[8];
    if (lane == 0) qnl[wv] = qn;
    __syncthreads();
    if (n < 4) {
        const float den = fmaxf(fabsf(qnl[2 * n] + qnl[2 * n + 1]), bcst[n][2]);
        scal[(size_t)(b * NHH + n) * 4 + 2] = 1.f / (den + EPSV);
    }
}

// ---------------- K3: fused C-update + nom + /den + layernorm + skip + silu(z) gate ----------------
// grid 256 (one block per (b,h)), block 512. One full 512x512 C tile per block.
// Thread: c4 = tid&127 (col quad), rg = tid>>7 (128-row group).
__global__ __launch_bounds__(512) void k_cupd_norm(
    const float* __restrict__ C_in, const float* __restrict__ qb,
    const float* __restrict__ kb, const float* __restrict__ vb,
    const float* __restrict__ scal, const float* __restrict__ norm_scale,
    const float* __restrict__ sact, const float* __restrict__ zsil,
    float* __restrict__ C_out, float* __restrict__ hbuf) {
    const int bh = blockIdx.x, b = bh >> 2, h = bh & 3;
    const int tid = threadIdx.x;
    const int c4 = tid & 127, rg = tid >> 7;
    __shared__ float qs[HDD], kik[HDD];
    const float f_p    = scal[bh * 4 + 0];
    const float ikv    = scal[bh * 4 + 1];
    const float invden = scal[bh * 4 + 2];
    qs[tid]  = qb[(size_t)b * HIDD + h * HDD + tid];
    kik[tid] = ikv * kb[(size_t)b * HIDD + h * HDD + tid];
    __syncthreads();
    const float4 v4 = *(const float4*)(vb + (size_t)b * HIDD + h * HDD + c4 * 4);
    float4 nom = {0.f, 0.f, 0.f, 0.f};
    const size_t base = ((size_t)bh * HDD + rg * 128) * HDD + c4 * 4;
    const float* __restrict__ cin  = C_in  + base;
    float* __restrict__ cout = C_out + base;
#pragma unroll 8
    for (int i = 0; i < 128; ++i) {
        const float4 c = *(const float4*)(cin + (size_t)i * HDD);
        const float kk = kik[rg * 128 + i];
        float4 cn;
        cn.x = f_p * c.x + kk * v4.x;
        cn.y = f_p * c.y + kk * v4.y;
        cn.z = f_p * c.z + kk * v4.z;
        cn.w = f_p * c.w + kk * v4.w;
        *(float4*)(cout + (size_t)i * HDD) = cn;
        const float qd = qs[rg * 128 + i];
        nom.x += qd * cn.x; nom.y += qd * cn.y; nom.z += qd * cn.z; nom.w += qd * cn.w;
    }
    __shared__ float4 rn[512];
    rn[tid] = nom;
    __syncthreads();
    __shared__ float Ls[2], Ls2[2];
    float4 ht = {0.f, 0.f, 0.f, 0.f};
    if (rg == 0) {
#pragma unroll
        for (int g = 1; g < 4; ++g) {
            const float4 o = rn[g * 128 + tid];
            nom.x += o.x; nom.y += o.y; nom.z += o.z; nom.w += o.w;
        }
        ht.x = nom.x * invden; ht.y = nom.y * invden;
        ht.z = nom.z * invden; ht.w = nom.w * invden;
        float s  = ht.x + ht.y + ht.z + ht.w;
        float sq = ht.x*ht.x + ht.y*ht.y + ht.z*ht.z + ht.w*ht.w;
#pragma unroll
        for (int off = 32; off > 0; off >>= 1) {
            s  += __shfl_down(s, off);
            sq += __shfl_down(sq, off);
        }
        if ((tid & 63) == 0) { Ls[tid >> 6] = s; Ls2[tid >> 6] = sq; }
    }
    __syncthreads();
    if (rg == 0) {
        const float mu  = (Ls[0] + Ls[1]) * (1.f / HDD);
        const float var = (Ls2[0] + Ls2[1]) * (1.f / HDD) - mu * mu;
        const float rs  = rsqrtf(var + EPSV);
        const size_t o = (size_t)b * HIDD + h * HDD + c4 * 4;
        const float4 nsc = *(const float4*)(norm_scale + (size_t)h * HDD + c4 * 4);
        const float4 sa  = *(const float4*)(sact + o);
        const float4 zs  = *(const float4*)(zsil + o);
        float4 val;
        val.x = ((ht.x - mu) * rs * nsc.x + sa.x) * zs.x;
        val.y = ((ht.y - mu) * rs * nsc.y + sa.y) * zs.y;
        val.z = ((ht.z - mu) * rs * nsc.z + sa.z) * zs.z;
        val.w = ((ht.w - mu) * rs * nsc.w + sa.w) * zs.w;
        *(float4*)(hbuf + o) = val;
    }
}

// ---------------- K4: down GEMM split-K, float4 A-reads ----------------
// grid (4 coltiles, 4 btiles, 16 kchunks) = 256 blocks, block 256.
__global__ __launch_bounds__(256) void k_down_part(const float* __restrict__ A,
                                                   const float* __restrict__ W,
                                                   float* __restrict__ part) {
    const int tid = threadIdx.x;
    const int c  = blockIdx.x * 256 + tid;
    const int b0 = blockIdx.y * 16;
    const int k0 = blockIdx.z * 128;
    __shared__ float As[16 * 128];
#pragma unroll
    for (int j = 0; j < 8; ++j) {
        const int e = j * 256 + tid;
        const int i = e >> 7, f = e & 127;
        As[e] = A[(size_t)(b0 + i) * HIDD + k0 + f];
    }
    __syncthreads();
    float acc[16];
#pragma unroll
    for (int i = 0; i < 16; ++i) acc[i] = 0.f;
    const float* __restrict__ wp = W + (size_t)k0 * FF + c;
#pragma unroll 2
    for (int f4 = 0; f4 < 32; ++f4) {
        const float w0 = wp[(size_t)(4*f4 + 0) * FF];
        const float w1 = wp[(size_t)(4*f4 + 1) * FF];
        const float w2 = wp[(size_t)(4*f4 + 2) * FF];
        const float w3 = wp[(size_t)(4*f4 + 3) * FF];
#pragma unroll
        for (int i = 0; i < 16; ++i) {
            const float4 a = *(const float4*)(As + i * 128 + f4 * 4);
            acc[i] += a.x * w0 + a.y * w1 + a.z * w2 + a.w * w3;
        }
    }
    float* __restrict__ pp = part + ((size_t)blockIdx.z * BB + b0) * FF + c;
#pragma unroll
    for (int i = 0; i < 16; ++i) pp[(size_t)i * FF] = acc[i];
}

// ---------------- K5: reduce 16 partials -> y ----------------
__global__ __launch_bounds__(256) void k_down_red(const float* __restrict__ part,
                                                  float* __restrict__ y) {
    const int i = (blockIdx.x * 256 + threadIdx.x) * 4;
    float4 s = *(const float4*)(part + i);
#pragma unroll
    for (int kc = 1; kc < 16; ++kc) {
        const float4 p = *(const float4*)(part + (size_t)kc * BB * FF + i);
        s.x += p.x; s.y += p.y; s.z += p.z; s.w += p.w;
    }
    *(float4*)(y + i) = s;
}

extern "C" void kernel_launch(void* const* d_in, const int* in_sizes, int n_in,
                              void* d_out, int out_size, void* d_ws, size_t ws_size,
                              hipStream_t stream) {
    const float* inputs     = (const float*)d_in[0];
    const float* C_in       = (const float*)d_in[1];
    const float* nstate_in  = (const float*)d_in[2];
    const float* mstate_in  = (const float*)d_in[3];
    const float* conv_state = (const float*)d_in[4];
    const float* W_up       = (const float*)d_in[5];
    const float* conv_w     = (const float*)d_in[6];
    const float* conv_b     = (const float*)d_in[7];
    const float* Wq         = (const float*)d_in[8];
    const float* Wk         = (const float*)d_in[9];
    const float* Wv         = (const float*)d_in[10];
    const float* Wi         = (const float*)d_in[11];
    const float* bi         = (const float*)d_in[12];
    const float* Wf         = (const float*)d_in[13];
    const float* bf         = (const float*)d_in[14];
    const float* norm_scale = (const float*)d_in[15];
    const float* skip       = (const float*)d_in[16];
    const float* W_down     = (const float*)d_in[17];

    float* ws = (float*)d_ws;
    float* part_up = ws;                  // 4*64*4096  = 1048576
    float* sact    = ws + 1048576;        // 131072 (skip*silu(conv))
    float* zsil    = sact + 131072;       // 131072 (z*sigmoid(z))
    float* qb      = zsil + 131072;       // 131072
    float* kb      = qb   + 131072;       // 131072
    float* vb      = kb   + 131072;       // 131072
    float* scal    = vb   + 131072;       // 1024
    float* hbuf    = scal + 1024;         // 131072
    float* part_y  = hbuf + 131072;       // 16*64*1024 = 1048576  (total ~11.5 MB)

    float* out_y  = (float*)d_out;        // 65536
    float* out_C  = out_y + 65536;        // 67108864
    float* out_n  = out_C + 67108864;     // 131072
    float* out_m  = out_n + 131072;       // 256
    float* out_cs = out_m + 256;          // 524288

    k_up_part  <<<dim3(16, 4, 4), 256, 0, stream>>>(inputs, W_up, part_up);
    k_mid      <<<BB,             512, 0, stream>>>(part_up, conv_state, conv_w, conv_b,
                                                    Wq, Wk, Wv, Wi, bi, Wf, bf,
                                                    mstate_in, nstate_in, skip,
                                                    out_cs, out_m, out_n,
                                                    sact, zsil, qb, kb, vb, scal);
    k_cupd_norm<<<BB * NHH,       512, 0, stream>>>(C_in, qb, kb, vb, scal, norm_scale,
                                                    sact, zsil, out_C, hbuf);
    k_down_part<<<dim3(4, 4, 16), 256, 0, stream>>>(hbuf, W_down, part_y);
    k_down_red <<<64,             256, 0, stream>>>(part_y, out_y);
}

// Round 2
// 544.633 us; speedup vs baseline: 1.0649x; 1.0649x over previous
//
#include <hip/hip_runtime.h>
#include <math.h>

#define BB   64
#define FF   1024
#define HIDD 2048
#define NHH  4
#define KSS  4
#define HDD  512
#define EPSV 1e-6f
#define INV_SQRT_HD 0.04419417382415922f  // 1/sqrt(512)

typedef float v4f __attribute__((ext_vector_type(4)));

// ---------------- K1: up GEMM split-K: part[kc][b][c] ----------------
// grid (16 coltiles, 8 btiles, 4 kchunks) = 512 blocks (2/CU, 2 waves/SIMD), block 256.
__global__ __launch_bounds__(256) void k_up_part(const float* __restrict__ A,
                                                 const float* __restrict__ W,
                                                 float* __restrict__ part) {
    const int tid = threadIdx.x;
    const int c  = blockIdx.x * 256 + tid;
    const int b0 = blockIdx.y * 8;
    const int k0 = blockIdx.z * 256;
    __shared__ float As[8 * 256];
#pragma unroll
    for (int j = 0; j < 8; ++j)
        As[j * 256 + tid] = A[(size_t)(b0 + j) * FF + k0 + tid];
    __syncthreads();
    float acc[8];
#pragma unroll
    for (int i = 0; i < 8; ++i) acc[i] = 0.f;
    const float* __restrict__ wp = W + (size_t)k0 * (2 * HIDD) + c;
#pragma unroll 2
    for (int f4 = 0; f4 < 64; ++f4) {
        const float w0 = wp[(size_t)(4*f4 + 0) * (2 * HIDD)];
        const float w1 = wp[(size_t)(4*f4 + 1) * (2 * HIDD)];
        const float w2 = wp[(size_t)(4*f4 + 2) * (2 * HIDD)];
        const float w3 = wp[(size_t)(4*f4 + 3) * (2 * HIDD)];
#pragma unroll
        for (int i = 0; i < 8; ++i) {
            const v4f a = *(const v4f*)(As + i * 256 + f4 * 4);
            acc[i] += a.x * w0 + a.y * w1 + a.z * w2 + a.w * w3;
        }
    }
    float* __restrict__ pp = part + ((size_t)blockIdx.z * BB + b0) * (2 * HIDD) + c;
#pragma unroll
    for (int i = 0; i < 8; ++i) pp[(size_t)i * (2 * HIDD)] = acc[i];
}

// ---------------- K2: fused up-reduce + conv + silu + qkv + gates + n/den ----------------
// grid 64 (one block per b), block 512. Thread n owns hid elements h0=n*4 .. h0+3.
__global__ __launch_bounds__(512) void k_mid(
    const float* __restrict__ part_up, const float* __restrict__ conv_state,
    const float* __restrict__ conv_w, const float* __restrict__ conv_b,
    const float* __restrict__ Wq, const float* __restrict__ Wk, const float* __restrict__ Wv,
    const float* __restrict__ Wi, const float* __restrict__ bi,
    const float* __restrict__ Wf, const float* __restrict__ bf,
    const float* __restrict__ mstate_in, const float* __restrict__ nstate_in,
    const float* __restrict__ skip,
    float* __restrict__ out_cs, float* __restrict__ out_m, float* __restrict__ out_n,
    float* __restrict__ sact, float* __restrict__ zsil,
    float* __restrict__ qb, float* __restrict__ kb, float* __restrict__ vb,
    float* __restrict__ scal) {
    const int b  = blockIdx.x;
    const int n  = threadIdx.x;
    const int h0 = n * 4;

    // ---- inline split-K reduce of x-half ----
    float4 x4 = *(const float4*)(part_up + (size_t)b * (2 * HIDD) + h0);
#pragma unroll
    for (int kc = 1; kc < 4; ++kc) {
        const float4 p = *(const float4*)(part_up + ((size_t)kc * BB + b) * (2 * HIDD) + h0);
        x4.x += p.x; x4.y += p.y; x4.z += p.z; x4.w += p.w;
    }
    // ---- inline split-K reduce of z-half + silu(z) ----
    float4 z4 = *(const float4*)(part_up + (size_t)b * (2 * HIDD) + HIDD + h0);
#pragma unroll
    for (int kc = 1; kc < 4; ++kc) {
        const float4 p = *(const float4*)(part_up + ((size_t)kc * BB + b) * (2 * HIDD) + HIDD + h0);
        z4.x += p.x; z4.y += p.y; z4.z += p.z; z4.w += p.w;
    }
    float4 zs;
    zs.x = z4.x / (1.f + expf(-z4.x));
    zs.y = z4.y / (1.f + expf(-z4.y));
    zs.z = z4.z / (1.f + expf(-z4.z));
    zs.w = z4.w / (1.f + expf(-z4.w));
    *(float4*)(zsil + (size_t)b * HIDD + h0) = zs;

    // ---- conv state shift + conv + silu ----
    const float4 cs1 = *(const float4*)(conv_state + (size_t)b * KSS * HIDD + 1 * HIDD + h0);
    const float4 cs2 = *(const float4*)(conv_state + (size_t)b * KSS * HIDD + 2 * HIDD + h0);
    const float4 cs3 = *(const float4*)(conv_state + (size_t)b * KSS * HIDD + 3 * HIDD + h0);
    *(float4*)(out_cs + (size_t)b * KSS * HIDD + 0 * HIDD + h0) = cs1;
    *(float4*)(out_cs + (size_t)b * KSS * HIDD + 1 * HIDD + h0) = cs2;
    *(float4*)(out_cs + (size_t)b * KSS * HIDD + 2 * HIDD + h0) = cs3;
    *(float4*)(out_cs + (size_t)b * KSS * HIDD + 3 * HIDD + h0) = x4;
    const float4 cw0 = *(const float4*)(conv_w + 0 * HIDD + h0);
    const float4 cw1 = *(const float4*)(conv_w + 1 * HIDD + h0);
    const float4 cw2 = *(const float4*)(conv_w + 2 * HIDD + h0);
    const float4 cw3 = *(const float4*)(conv_w + 3 * HIDD + h0);
    const float4 cb  = *(const float4*)(conv_b + h0);
    float4 cx;
    cx.x = cs1.x*cw0.x + cs2.x*cw1.x + cs3.x*cw2.x + x4.x*cw3.x + cb.x;
    cx.y = cs1.y*cw0.y + cs2.y*cw1.y + cs3.y*cw2.y + x4.y*cw3.y + cb.y;
    cx.z = cs1.z*cw0.z + cs2.z*cw1.z + cs3.z*cw2.z + x4.z*cw3.z + cb.z;
    cx.w = cs1.w*cw0.w + cs2.w*cw1.w + cs3.w*cw2.w + x4.w*cw3.w + cb.w;
    float4 a4;
    a4.x = cx.x / (1.f + expf(-cx.x));
    a4.y = cx.y / (1.f + expf(-cx.y));
    a4.z = cx.z / (1.f + expf(-cx.z));
    a4.w = cx.w / (1.f + expf(-cx.w));
    const float4 sk = *(const float4*)(skip + h0);
    float4 sa;
    sa.x = sk.x * a4.x; sa.y = sk.y * a4.y; sa.z = sk.z * a4.z; sa.w = sk.w * a4.w;
    *(float4*)(sact + (size_t)b * HIDD + h0) = sa;

    // ---- blockdiag q/k/v ----
    const float4 q0 = *(const float4*)(Wq + (size_t)n * 16 + 0);
    const float4 q1 = *(const float4*)(Wq + (size_t)n * 16 + 4);
    const float4 q2 = *(const float4*)(Wq + (size_t)n * 16 + 8);
    const float4 q3 = *(const float4*)(Wq + (size_t)n * 16 + 12);
    float4 qv4;
    qv4.x = a4.x*q0.x + a4.y*q1.x + a4.z*q2.x + a4.w*q3.x;
    qv4.y = a4.x*q0.y + a4.y*q1.y + a4.z*q2.y + a4.w*q3.y;
    qv4.z = a4.x*q0.z + a4.y*q1.z + a4.z*q2.z + a4.w*q3.z;
    qv4.w = a4.x*q0.w + a4.y*q1.w + a4.z*q2.w + a4.w*q3.w;
    *(float4*)(qb + (size_t)b * HIDD + h0) = qv4;
    const float4 k0v = *(const float4*)(Wk + (size_t)n * 16 + 0);
    const float4 k1v = *(const float4*)(Wk + (size_t)n * 16 + 4);
    const float4 k2v = *(const float4*)(Wk + (size_t)n * 16 + 8);
    const float4 k3v = *(const float4*)(Wk + (size_t)n * 16 + 12);
    float4 kv4;
    kv4.x = a4.x*k0v.x + a4.y*k1v.x + a4.z*k2v.x + a4.w*k3v.x;
    kv4.y = a4.x*k0v.y + a4.y*k1v.y + a4.z*k2v.y + a4.w*k3v.y;
    kv4.z = a4.x*k0v.z + a4.y*k1v.z + a4.z*k2v.z + a4.w*k3v.z;
    kv4.w = a4.x*k0v.w + a4.y*k1v.w + a4.z*k2v.w + a4.w*k3v.w;
    *(float4*)(kb + (size_t)b * HIDD + h0) = kv4;
    const float4 v0 = *(const float4*)(Wv + (size_t)n * 16 + 0);
    const float4 v1 = *(const float4*)(Wv + (size_t)n * 16 + 4);
    const float4 v2 = *(const float4*)(Wv + (size_t)n * 16 + 8);
    const float4 v3 = *(const float4*)(Wv + (size_t)n * 16 + 12);
    float4 vv4;
    vv4.x = x4.x*v0.x + x4.y*v1.x + x4.z*v2.x + x4.w*v3.x;
    vv4.y = x4.x*v0.y + x4.y*v1.y + x4.z*v2.y + x4.w*v3.y;
    vv4.z = x4.x*v0.z + x4.y*v1.z + x4.z*v2.z + x4.w*v3.z;
    vv4.w = x4.x*v0.w + x4.y*v1.w + x4.z*v2.w + x4.w*v3.w;
    *(float4*)(vb + (size_t)b * HIDD + h0) = vv4;

    // ---- gate reductions i/f for 4 heads (wave-shuffle, float4 Wi/Wf rows) ----
    float si0 = 0.f, si1 = 0.f, si2 = 0.f, si3 = 0.f;
    float sf0 = 0.f, sf1 = 0.f, sf2 = 0.f, sf3 = 0.f;
#define GATE_R(comp, r) { \
    const float qr = qv4.comp, kr = kv4.comp, vr = vv4.comp; \
    const float4 wq_ = *(const float4*)(Wi + (size_t)(h0 + (r)) * NHH); \
    const float4 wk_ = *(const float4*)(Wi + (size_t)(HIDD + h0 + (r)) * NHH); \
    const float4 wv_ = *(const float4*)(Wi + (size_t)(2*HIDD + h0 + (r)) * NHH); \
    si0 += qr*wq_.x + kr*wk_.x + vr*wv_.x; \
    si1 += qr*wq_.y + kr*wk_.y + vr*wv_.y; \
    si2 += qr*wq_.z + kr*wk_.z + vr*wv_.z; \
    si3 += qr*wq_.w + kr*wk_.w + vr*wv_.w; \
    const float4 fq_ = *(const float4*)(Wf + (size_t)(h0 + (r)) * NHH); \
    const float4 fk_ = *(const float4*)(Wf + (size_t)(HIDD + h0 + (r)) * NHH); \
    const float4 fv_ = *(const float4*)(Wf + (size_t)(2*HIDD + h0 + (r)) * NHH); \
    sf0 += qr*fq_.x + kr*fk_.x + vr*fv_.x; \
    sf1 += qr*fq_.y + kr*fk_.y + vr*fv_.y; \
    sf2 += qr*fq_.z + kr*fk_.z + vr*fv_.z; \
    sf3 += qr*fq_.w + kr*fk_.w + vr*fv_.w; \
}
    GATE_R(x, 0) GATE_R(y, 1) GATE_R(z, 2) GATE_R(w, 3)
#undef GATE_R
#pragma unroll
    for (int off = 32; off > 0; off >>= 1) {
        si0 += __shfl_down(si0, off); si1 += __shfl_down(si1, off);
        si2 += __shfl_down(si2, off); si3 += __shfl_down(si3, off);
        sf0 += __shfl_down(sf0, off); sf1 += __shfl_down(sf1, off);
        sf2 += __shfl_down(sf2, off); sf3 += __shfl_down(sf3, off);
    }
    const int lane = n & 63, wv = n >> 6;
    __shared__ float Ls[8][8];
    if (lane == 0) {
        Ls[wv][0] = si0; Ls[wv][1] = si1; Ls[wv][2] = si2; Ls[wv][3] = si3;
        Ls[wv][4] = sf0; Ls[wv][5] = sf1; Ls[wv][6] = sf2; Ls[wv][7] = sf3;
    }
    __syncthreads();
    __shared__ float bcst[4][3];  // f_p, ik, exp(-m_new) per head
    if (n < 4) {
        float it = bi[n], ft = bf[n];
#pragma unroll
        for (int w = 0; w < 8; ++w) { it += Ls[w][n]; ft += Ls[w][4 + n]; }
        const float log_f = fminf(ft, 0.f) - log1pf(expf(-fabsf(ft)));
        const float m_old = mstate_in[b * NHH + n];
        const float m_new = fmaxf(log_f + m_old, it);
        out_m[b * NHH + n] = m_new;
        const float f_p = expf(log_f + m_old - m_new);
        const float ikv = expf(it - m_new) * INV_SQRT_HD;
        bcst[n][0] = f_p; bcst[n][1] = ikv; bcst[n][2] = expf(-m_new);
        float* sc = scal + (size_t)(b * NHH + n) * 4;
        sc[0] = f_p; sc[1] = ikv;
    }
    __syncthreads();

    // ---- n_new + den ----
    const int h  = n >> 7;
    const int bh = b * NHH + h;
    const float f_p = bcst[h][0], ikv = bcst[h][1];
    const int d0 = (n & 127) * 4;
    const float4 nin = *(const float4*)(nstate_in + (size_t)bh * HDD + d0);
    float4 nn;
    nn.x = f_p * nin.x + ikv * kv4.x;
    nn.y = f_p * nin.y + ikv * kv4.y;
    nn.z = f_p * nin.z + ikv * kv4.z;
    nn.w = f_p * nin.w + ikv * kv4.w;
    *(float4*)(out_n + (size_t)bh * HDD + d0) = nn;
    float qn = qv4.x * nn.x + qv4.y * nn.y + qv4.z * nn.z + qv4.w * nn.w;
#pragma unroll
    for (int off = 32; off > 0; off >>= 1) qn += __shfl_down(qn, off);
    __shared__ float qnl[8];
    if (lane == 0) qnl[wv] = qn;
    __syncthreads();
    if (n < 4) {
        const float den = fmaxf(fabsf(qnl[2 * n] + qnl[2 * n + 1]), bcst[n][2]);
        scal[(size_t)(b * NHH + n) * 4 + 2] = 1.f / (den + EPSV);
    }
}

// ---------------- K3: fused C-update + nom + /den + layernorm + skip + silu(z) gate ----------------
// grid 256 (one block per (b,h)), block 1024 (16 waves/CU). 64 rows/thread.
// Nontemporal on the 537 MB C stream (touch-once; keep L2/L3 clean).
__global__ __launch_bounds__(1024) void k_cupd_norm(
    const float* __restrict__ C_in, const float* __restrict__ qb,
    const float* __restrict__ kb, const float* __restrict__ vb,
    const float* __restrict__ scal, const float* __restrict__ norm_scale,
    const float* __restrict__ sact, const float* __restrict__ zsil,
    float* __restrict__ C_out, float* __restrict__ hbuf) {
    const int bh = blockIdx.x, b = bh >> 2, h = bh & 3;
    const int tid = threadIdx.x;
    const int c4 = tid & 127, rg = tid >> 7;   // rg in [0,8): 64-row group
    __shared__ float qs[HDD], kik[HDD];
    const float f_p    = scal[bh * 4 + 0];
    const float ikv    = scal[bh * 4 + 1];
    const float invden = scal[bh * 4 + 2];
    if (tid < HDD) qs[tid] = qb[(size_t)b * HIDD + h * HDD + tid];
    else           kik[tid - HDD] = ikv * kb[(size_t)b * HIDD + h * HDD + (tid - HDD)];
    __syncthreads();
    const v4f v4 = *(const v4f*)(vb + (size_t)b * HIDD + h * HDD + c4 * 4);
    v4f nom = {0.f, 0.f, 0.f, 0.f};
    const size_t base = ((size_t)bh * HDD + rg * 64) * HDD + c4 * 4;
    const float* __restrict__ cin  = C_in  + base;
    float* __restrict__ cout = C_out + base;
#pragma unroll 8
    for (int i = 0; i < 64; ++i) {
        const v4f c = __builtin_nontemporal_load((const v4f*)(cin + (size_t)i * HDD));
        const float kk = kik[rg * 64 + i];
        v4f cn;
        cn.x = f_p * c.x + kk * v4.x;
        cn.y = f_p * c.y + kk * v4.y;
        cn.z = f_p * c.z + kk * v4.z;
        cn.w = f_p * c.w + kk * v4.w;
        __builtin_nontemporal_store(cn, (v4f*)(cout + (size_t)i * HDD));
        const float qd = qs[rg * 64 + i];
        nom.x += qd * cn.x; nom.y += qd * cn.y; nom.z += qd * cn.z; nom.w += qd * cn.w;
    }
    __shared__ v4f rn[1024];
    rn[tid] = nom;
    __syncthreads();
    __shared__ float Ls[2], Ls2[2];
    v4f ht = {0.f, 0.f, 0.f, 0.f};
    if (rg == 0) {
#pragma unroll
        for (int g = 1; g < 8; ++g) {
            const v4f o = rn[g * 128 + tid];
            nom.x += o.x; nom.y += o.y; nom.z += o.z; nom.w += o.w;
        }
        ht.x = nom.x * invden; ht.y = nom.y * invden;
        ht.z = nom.z * invden; ht.w = nom.w * invden;
        float s  = ht.x + ht.y + ht.z + ht.w;
        float sq = ht.x*ht.x + ht.y*ht.y + ht.z*ht.z + ht.w*ht.w;
#pragma unroll
        for (int off = 32; off > 0; off >>= 1) {
            s  += __shfl_down(s, off);
            sq += __shfl_down(sq, off);
        }
        if ((tid & 63) == 0) { Ls[tid >> 6] = s; Ls2[tid >> 6] = sq; }
    }
    __syncthreads();
    if (rg == 0) {
        const float mu  = (Ls[0] + Ls[1]) * (1.f / HDD);
        const float var = (Ls2[0] + Ls2[1]) * (1.f / HDD) - mu * mu;
        const float rs  = rsqrtf(var + EPSV);
        const size_t o = (size_t)b * HIDD + h * HDD + c4 * 4;
        const float4 nsc = *(const float4*)(norm_scale + (size_t)h * HDD + c4 * 4);
        const float4 sa  = *(const float4*)(sact + o);
        const float4 zs  = *(const float4*)(zsil + o);
        float4 val;
        val.x = ((ht.x - mu) * rs * nsc.x + sa.x) * zs.x;
        val.y = ((ht.y - mu) * rs * nsc.y + sa.y) * zs.y;
        val.z = ((ht.z - mu) * rs * nsc.z + sa.z) * zs.z;
        val.w = ((ht.w - mu) * rs * nsc.w + sa.w) * zs.w;
        *(float4*)(hbuf + o) = val;
    }
}

// ---------------- K4: down GEMM split-K, btile=8 ----------------
// grid (4 coltiles, 8 btiles, 16 kchunks) = 512 blocks (2/CU), block 256.
__global__ __launch_bounds__(256) void k_down_part(const float* __restrict__ A,
                                                   const float* __restrict__ W,
                                                   float* __restrict__ part) {
    const int tid = threadIdx.x;
    const int c  = blockIdx.x * 256 + tid;
    const int b0 = blockIdx.y * 8;
    const int k0 = blockIdx.z * 128;
    __shared__ float As[8 * 128];
#pragma unroll
    for (int j = 0; j < 4; ++j) {
        const int e = j * 256 + tid;
        const int i = e >> 7, f = e & 127;
        As[e] = A[(size_t)(b0 + i) * HIDD + k0 + f];
    }
    __syncthreads();
    float acc[8];
#pragma unroll
    for (int i = 0; i < 8; ++i) acc[i] = 0.f;
    const float* __restrict__ wp = W + (size_t)k0 * FF + c;
#pragma unroll 2
    for (int f4 = 0; f4 < 32; ++f4) {
        const float w0 = wp[(size_t)(4*f4 + 0) * FF];
        const float w1 = wp[(size_t)(4*f4 + 1) * FF];
        const float w2 = wp[(size_t)(4*f4 + 2) * FF];
        const float w3 = wp[(size_t)(4*f4 + 3) * FF];
#pragma unroll
        for (int i = 0; i < 8; ++i) {
            const v4f a = *(const v4f*)(As + i * 128 + f4 * 4);
            acc[i] += a.x * w0 + a.y * w1 + a.z * w2 + a.w * w3;
        }
    }
    float* __restrict__ pp = part + ((size_t)blockIdx.z * BB + b0) * FF + c;
#pragma unroll
    for (int i = 0; i < 8; ++i) pp[(size_t)i * FF] = acc[i];
}

// ---------------- K5: reduce 16 partials -> y ----------------
__global__ __launch_bounds__(256) void k_down_red(const float* __restrict__ part,
                                                  float* __restrict__ y) {
    const int i = (blockIdx.x * 256 + threadIdx.x) * 4;
    float4 s = *(const float4*)(part + i);
#pragma unroll
    for (int kc = 1; kc < 16; ++kc) {
        const float4 p = *(const float4*)(part + (size_t)kc * BB * FF + i);
        s.x += p.x; s.y += p.y; s.z += p.z; s.w += p.w;
    }
    *(float4*)(y + i) = s;
}

extern "C" void kernel_launch(void* const* d_in, const int* in_sizes, int n_in,
                              void* d_out, int out_size, void* d_ws, size_t ws_size,
                              hipStream_t stream) {
    const float* inputs     = (const float*)d_in[0];
    const float* C_in       = (const float*)d_in[1];
    const float* nstate_in  = (const float*)d_in[2];
    const float* mstate_in  = (const float*)d_in[3];
    const float* conv_state = (const float*)d_in[4];
    const float* W_up       = (const float*)d_in[5];
    const float* conv_w     = (const float*)d_in[6];
    const float* conv_b     = (const float*)d_in[7];
    const float* Wq         = (const float*)d_in[8];
    const float* Wk         = (const float*)d_in[9];
    const float* Wv         = (const float*)d_in[10];
    const float* Wi         = (const float*)d_in[11];
    const float* bi         = (const float*)d_in[12];
    const float* Wf         = (const float*)d_in[13];
    const float* bf         = (const float*)d_in[14];
    const float* norm_scale = (const float*)d_in[15];
    const float* skip       = (const float*)d_in[16];
    const float* W_down     = (const float*)d_in[17];

    float* ws = (float*)d_ws;
    float* part_up = ws;                  // 4*64*4096  = 1048576
    float* sact    = ws + 1048576;        // 131072 (skip*silu(conv))
    float* zsil    = sact + 131072;       // 131072 (z*sigmoid(z))
    float* qb      = zsil + 131072;       // 131072
    float* kb      = qb   + 131072;       // 131072
    float* vb      = kb   + 131072;       // 131072
    float* scal    = vb   + 131072;       // 1024
    float* hbuf    = scal + 1024;         // 131072
    float* part_y  = hbuf + 131072;       // 16*64*1024 = 1048576  (total ~11.5 MB)

    float* out_y  = (float*)d_out;        // 65536
    float* out_C  = out_y + 65536;        // 67108864
    float* out_n  = out_C + 67108864;     // 131072
    float* out_m  = out_n + 131072;       // 256
    float* out_cs = out_m + 256;          // 524288

    k_up_part  <<<dim3(16, 8, 4),  256,  0, stream>>>(inputs, W_up, part_up);
    k_mid      <<<BB,              512,  0, stream>>>(part_up, conv_state, conv_w, conv_b,
                                                      Wq, Wk, Wv, Wi, bi, Wf, bf,
                                                      mstate_in, nstate_in, skip,
                                                      out_cs, out_m, out_n,
                                                      sact, zsil, qb, kb, vb, scal);
    k_cupd_norm<<<BB * NHH,        1024, 0, stream>>>(C_in, qb, kb, vb, scal, norm_scale,
                                                      sact, zsil, out_C, hbuf);
    k_down_part<<<dim3(4, 8, 16),  256,  0, stream>>>(hbuf, W_down, part_y);
    k_down_red <<<64,              256,  0, stream>>>(part_y, out_y);
}